// Round 18
// baseline (1057.786 us; speedup 1.0000x reference)
//
#include <hip/hip_runtime.h>

#define NCH   256
#define M_PIX 262144
#define MPAD  266240   // 520*512 ; >= M_PIX + 8*512 worst-case alignment pad
#define LDA   40       // padded LDS leading dim (bf16 elements) for 32-wide k tiles

typedef short bf16x8 __attribute__((ext_vector_type(8)));
typedef float f32x4  __attribute__((ext_vector_type(4)));

__device__ __forceinline__ unsigned short f2bf(float f) {
  union { float f; unsigned u; } v; v.f = f;
  unsigned r = v.u + 0x7FFFu + ((v.u >> 16) & 1u);
  return (unsigned short)(r >> 16);
}
__device__ __forceinline__ float bf2f(unsigned short h) {
  union { unsigned u; float f; } v; v.u = ((unsigned)h) << 16;
  return v.f;
}

// ---------------- histogram: per-2048-pixel-block label counts, both segs ----
__global__ __launch_bounds__(256) void k_hist(const int* __restrict__ seg_c,
                                              const int* __restrict__ seg_s,
                                              int* __restrict__ hist) {
  __shared__ int h[16];
  int t = threadIdx.x;
  if (t < 16) h[t] = 0;
  __syncthreads();
  int p0 = blockIdx.x * 2048 + t * 8;
#pragma unroll
  for (int e = 0; e < 8; ++e) {
    atomicAdd(&h[seg_c[p0 + e] & 7], 1);
    atomicAdd(&h[8 + (seg_s[p0 + e] & 7)], 1);
  }
  __syncthreads();
  if (t < 8) hist[blockIdx.x * 8 + t] = h[t];
  else if (t < 16) hist[1024 + blockIdx.x * 8 + (t - 8)] = h[t];
}

// ---------------- scan: totals, 512-aligned offsets, per-block bases, valid --
__global__ __launch_bounds__(256) void k_scan(const int* __restrict__ hist,
                                              int* __restrict__ base,
                                              int* __restrict__ off,
                                              int* __restrict__ cnt,
                                              int* __restrict__ valid) {
  __shared__ int lh[2048];
  __shared__ int tot[16];
  __shared__ int loff[2][9];
  int t = threadIdx.x;
  for (int i = t; i < 2048; i += 256) lh[i] = hist[i];
  __syncthreads();
  if (t < 16) {
    int s = t >> 3, l = t & 7, acc = 0;
    for (int b = 0; b < 128; ++b) acc += lh[s * 1024 + b * 8 + l];
    tot[t] = acc;
  }
  __syncthreads();
  if (t < 2) {
    int run = 0;
    for (int l = 0; l < 8; ++l) {
      loff[t][l] = run;
      run = (run + tot[t * 8 + l] + 511) & ~511;
    }
    loff[t][8] = run;
    for (int l = 0; l < 9; ++l) off[t * 9 + l] = loff[t][l];
    for (int l = 0; l < 8; ++l) cnt[t * 8 + l] = tot[t * 8 + l];
  }
  __syncthreads();
  if (t < 8) {
    long nc = tot[t], ns = tot[8 + t];
    valid[t] = (nc > 10 && ns > 10 && nc < 100 * ns && ns < 100 * nc) ? 1 : 0;
  }
  if (t < 16) {
    int s = t >> 3, l = t & 7;
    int run = loff[s][l];
    for (int b = 0; b < 128; ++b) {
      base[s * 1024 + b * 8 + l] = run;
      run += lh[s * 1024 + b * 8 + l];
    }
  }
}

// ---------------- rank: stable per-pixel destination slot (counting sort) ----
__global__ __launch_bounds__(256) void k_rank(const int* __restrict__ seg_c,
                                              const int* __restrict__ seg_s,
                                              const int* __restrict__ base,
                                              int* __restrict__ dst) {
  __shared__ int sc[8 * 272];
  __shared__ int rb[256 * 8];
  __shared__ int bb[8];
  int t = threadIdx.x;
  for (int s = 0; s < 2; ++s) {
    const int* seg = s ? seg_s : seg_c;
    const int* bas = base + s * 1024 + blockIdx.x * 8;
    int* dd = dst + (size_t)s * M_PIX;
    int p0 = blockIdx.x * 2048 + t * 8;
    unsigned pk2 = 0, cpk = 0;
#pragma unroll
    for (int e = 0; e < 8; ++e) {
      int lb = seg[p0 + e] & 7;
      pk2 |= (unsigned)lb << (3 * e);
      cpk += 1u << (4 * lb);
    }
#pragma unroll
    for (int lq = 0; lq < 8; ++lq) sc[lq * 272 + t] = (int)((cpk >> (4 * lq)) & 15u);
    if (t < 8) bb[t] = bas[t];
    __syncthreads();
    for (int d = 1; d < 256; d <<= 1) {
      int v[8];
#pragma unroll
      for (int lq = 0; lq < 8; ++lq)
        v[lq] = sc[lq * 272 + t] + ((t >= d) ? sc[lq * 272 + t - d] : 0);
      __syncthreads();
#pragma unroll
      for (int lq = 0; lq < 8; ++lq) sc[lq * 272 + t] = v[lq];
      __syncthreads();
    }
#pragma unroll
    for (int lq = 0; lq < 8; ++lq)
      rb[t * 8 + lq] = bb[lq] + sc[lq * 272 + t] - (int)((cpk >> (4 * lq)) & 15u);
#pragma unroll
    for (int e = 0; e < 8; ++e) {
      int lb = (int)((pk2 >> (3 * e)) & 7u);
      int dpos = rb[t * 8 + lb]++;
      dd[p0 + e] = dpos;
    }
    __syncthreads();
  }
}

// ---------------- zero the alignment pads of P (within-label pads only) ------
__global__ __launch_bounds__(256) void k_padzero(unsigned short* __restrict__ P,
                                                 const int* __restrict__ off,
                                                 const int* __restrict__ cnt) {
  int l = blockIdx.x;
  int c0 = off[l] + cnt[l], c1 = off[l + 1];
  int w = c1 - c0;
  if (w <= 0) return;
  int r0 = blockIdx.y * 16;
  for (int r = r0; r < r0 + 16; ++r)
    for (int cc = threadIdx.x; cc < w; cc += 256)
      P[(size_t)r * MPAD + c0 + cc] = 0;
}

// ---------------- pack: coalesced-both-sides via LDS local sort --------------
__global__ __launch_bounds__(256) void k_pack(const float* __restrict__ feat,
                                              const int* __restrict__ seg,
                                              const int* __restrict__ dst,
                                              const int* __restrict__ base,
                                              unsigned short* __restrict__ P) {
  int b = blockIdx.x, g = blockIdx.y, t = threadIdx.x;
  int p0 = b * 2048;
  __shared__ unsigned short buf[8][2048];
  __shared__ int h[8], lbase[9], gbase[8];
  if (t < 8) { h[t] = 0; gbase[t] = base[b * 8 + t]; }
  __syncthreads();
  int lbr[2][4], slotr[2][4], gd[8];
#pragma unroll
  for (int j = 0; j < 2; ++j) {
    int4 sg = *(const int4*)&seg[p0 + j * 1024 + t * 4];
    lbr[j][0] = sg.x & 7; lbr[j][1] = sg.y & 7;
    lbr[j][2] = sg.z & 7; lbr[j][3] = sg.w & 7;
#pragma unroll
    for (int e = 0; e < 4; ++e) atomicAdd(&h[lbr[j][e]], 1);
  }
  __syncthreads();
  if (t == 0) {
    int run = 0;
    for (int l = 0; l < 8; ++l) { lbase[l] = run; run += h[l]; }
    lbase[8] = run;
  }
  __syncthreads();
#pragma unroll
  for (int j = 0; j < 2; ++j) {
    int4 dv = *(const int4*)&dst[p0 + j * 1024 + t * 4];
    slotr[j][0] = lbase[lbr[j][0]] + (dv.x - gbase[lbr[j][0]]);
    slotr[j][1] = lbase[lbr[j][1]] + (dv.y - gbase[lbr[j][1]]);
    slotr[j][2] = lbase[lbr[j][2]] + (dv.z - gbase[lbr[j][2]]);
    slotr[j][3] = lbase[lbr[j][3]] + (dv.w - gbase[lbr[j][3]]);
  }
#pragma unroll
  for (int i = 0; i < 8; ++i) {
    int q = i * 256 + t;
    int l = 0;
    while (l < 7 && q >= lbase[l + 1]) ++l;
    gd[i] = gbase[l] + q - lbase[l];
  }
  int n0 = g * 32;
#pragma unroll 1
  for (int cp = 0; cp < 4; ++cp) {
#pragma unroll
    for (int c = 0; c < 8; ++c) {
      const float* fp = &feat[(size_t)(n0 + cp * 8 + c) * M_PIX + p0];
      float4 v0 = *(const float4*)&fp[t * 4];
      float4 v1 = *(const float4*)&fp[1024 + t * 4];
      buf[c][slotr[0][0]] = f2bf(v0.x); buf[c][slotr[0][1]] = f2bf(v0.y);
      buf[c][slotr[0][2]] = f2bf(v0.z); buf[c][slotr[0][3]] = f2bf(v0.w);
      buf[c][slotr[1][0]] = f2bf(v1.x); buf[c][slotr[1][1]] = f2bf(v1.y);
      buf[c][slotr[1][2]] = f2bf(v1.z); buf[c][slotr[1][3]] = f2bf(v1.w);
    }
    __syncthreads();
#pragma unroll
    for (int c = 0; c < 8; ++c) {
      unsigned short* pp = &P[(size_t)(n0 + cp * 8 + c) * MPAD];
#pragma unroll
      for (int i = 0; i < 8; ++i)
        pp[gd[i]] = buf[c][i * 256 + t];
    }
    __syncthreads();
  }
}

// ---------------- unpack: mirrored (contiguous P reads, float4 out stores) ---
__global__ __launch_bounds__(256) void k_unpack(const unsigned short* __restrict__ P,
                                                const int* __restrict__ seg,
                                                const int* __restrict__ dst,
                                                const int* __restrict__ base,
                                                float* __restrict__ out) {
  int b = blockIdx.x, g = blockIdx.y, t = threadIdx.x;
  int p0 = b * 2048;
  __shared__ unsigned short buf[8][2048];
  __shared__ int h[8], lbase[9], gbase[8];
  if (t < 8) { h[t] = 0; gbase[t] = base[b * 8 + t]; }
  __syncthreads();
  int lbr[2][4], slotr[2][4], gd[8];
#pragma unroll
  for (int j = 0; j < 2; ++j) {
    int4 sg = *(const int4*)&seg[p0 + j * 1024 + t * 4];
    lbr[j][0] = sg.x & 7; lbr[j][1] = sg.y & 7;
    lbr[j][2] = sg.z & 7; lbr[j][3] = sg.w & 7;
#pragma unroll
    for (int e = 0; e < 4; ++e) atomicAdd(&h[lbr[j][e]], 1);
  }
  __syncthreads();
  if (t == 0) {
    int run = 0;
    for (int l = 0; l < 8; ++l) { lbase[l] = run; run += h[l]; }
    lbase[8] = run;
  }
  __syncthreads();
#pragma unroll
  for (int j = 0; j < 2; ++j) {
    int4 dv = *(const int4*)&dst[p0 + j * 1024 + t * 4];
    slotr[j][0] = lbase[lbr[j][0]] + (dv.x - gbase[lbr[j][0]]);
    slotr[j][1] = lbase[lbr[j][1]] + (dv.y - gbase[lbr[j][1]]);
    slotr[j][2] = lbase[lbr[j][2]] + (dv.z - gbase[lbr[j][2]]);
    slotr[j][3] = lbase[lbr[j][3]] + (dv.w - gbase[lbr[j][3]]);
  }
#pragma unroll
  for (int i = 0; i < 8; ++i) {
    int q = i * 256 + t;
    int l = 0;
    while (l < 7 && q >= lbase[l + 1]) ++l;
    gd[i] = gbase[l] + q - lbase[l];
  }
  int n0 = g * 32;
#pragma unroll 1
  for (int cp = 0; cp < 4; ++cp) {
#pragma unroll
    for (int c = 0; c < 8; ++c) {
      const unsigned short* pp = &P[(size_t)(n0 + cp * 8 + c) * MPAD];
#pragma unroll
      for (int i = 0; i < 8; ++i)
        buf[c][i * 256 + t] = pp[gd[i]];
    }
    __syncthreads();
#pragma unroll
    for (int c = 0; c < 8; ++c) {
      float* op = &out[(size_t)(n0 + cp * 8 + c) * M_PIX + p0];
      float4 v0, v1;
      v0.x = bf2f(buf[c][slotr[0][0]]); v0.y = bf2f(buf[c][slotr[0][1]]);
      v0.z = bf2f(buf[c][slotr[0][2]]); v0.w = bf2f(buf[c][slotr[0][3]]);
      v1.x = bf2f(buf[c][slotr[1][0]]); v1.y = bf2f(buf[c][slotr[1][1]]);
      v1.z = bf2f(buf[c][slotr[1][2]]); v1.w = bf2f(buf[c][slotr[1][3]]);
      *(float4*)&op[t * 4] = v0;
      *(float4*)&op[1024 + t * 4] = v1;
    }
    __syncthreads();
  }
}

// ---------------- Gram off-diag quadrant (rows 128.. x cols 0..) + psum ------
__global__ __launch_bounds__(256) void k_gram_off(const unsigned short* __restrict__ P,
                                                  const int* __restrict__ off,
                                                  float* __restrict__ G,
                                                  float* __restrict__ sum) {
  int l = blockIdx.y;
  long o0 = off[l], o1 = off[l + 1];
  long k0 = o0 + (long)blockIdx.x * 1024;
  if (k0 >= o1) return;
  long rem = o1 - k0;
  int ks = rem > 1024 ? 1024 : (int)rem;     // multiple of 512

  __shared__ unsigned short As[128 * LDA];   // rows 128..255
  __shared__ unsigned short Bs[128 * LDA];   // rows 0..127

  int t = threadIdx.x;
  int wave = t >> 6, lane = t & 63;
  int wr = (wave >> 1) * 64, wc = (wave & 1) * 64;

  f32x4 acc[4][4] = {};
  float rsum = 0.0f;

  for (int kk = 0; kk < ks; kk += 32) {
#pragma unroll
    for (int it = 0; it < 2; ++it) {
      int slot = t + it * 256;
      int rr = slot >> 2, gg = slot & 3;
      *(uint4*)&As[rr * LDA + gg * 8] =
          *(const uint4*)&P[(size_t)(128 + rr) * MPAD + (size_t)(k0 + kk) + gg * 8];
      *(uint4*)&Bs[rr * LDA + gg * 8] =
          *(const uint4*)&P[(size_t)rr * MPAD + (size_t)(k0 + kk) + gg * 8];
    }
    __syncthreads();
    {                                         // fused psum: all 256 rows
      const unsigned short* src = (t < 128) ? &As[t * LDA] : &Bs[(t - 128) * LDA];
#pragma unroll
      for (int e = 0; e < 16; ++e) {
        unsigned v = *(const unsigned*)&src[e * 2];
        rsum += bf2f((unsigned short)(v & 0xFFFFu)) + bf2f((unsigned short)(v >> 16));
      }
    }
    bf16x8 bfr[4];
#pragma unroll
    for (int fj = 0; fj < 4; ++fj)
      bfr[fj] = *(const bf16x8*)&Bs[(wc + fj * 16 + (lane & 15)) * LDA + (lane >> 4) * 8];
#pragma unroll
    for (int fi = 0; fi < 4; ++fi) {
      bf16x8 afr = *(const bf16x8*)&As[(wr + fi * 16 + (lane & 15)) * LDA + (lane >> 4) * 8];
#pragma unroll
      for (int fj = 0; fj < 4; ++fj)
        acc[fi][fj] = __builtin_amdgcn_mfma_f32_16x16x32_bf16(afr, bfr[fj], acc[fi][fj], 0, 0, 0);
    }
    __syncthreads();
  }
  float* Gl = G + ((size_t)l << 16);
  int rb = 128 + wr, cb = wc;
#pragma unroll
  for (int fi = 0; fi < 4; ++fi)
#pragma unroll
    for (int fj = 0; fj < 4; ++fj) {
      int cc = cb + fj * 16 + (lane & 15);
#pragma unroll
      for (int rg = 0; rg < 4; ++rg) {
        int rr = rb + fi * 16 + (lane >> 4) * 4 + rg;
        atomicAdd(&Gl[rr * 256 + cc], acc[fi][fj][rg]);
      }
    }
  {
    int row = (t < 128) ? (128 + t) : (t - 128);
    atomicAdd(&sum[l * 256 + row], rsum);
  }
}

// ---------------- Gram diag quadrant: ONE staged tile, 3 waves, lower only ---
// cov reads only G's lower triangle, so the (0..63 x 64..127) sub-tile of each
// diagonal quadrant is dead. 3 waves own sub-tiles (0,0),(64,0),(64,64); both
// MFMA operands come from the single staged tile (staging 6->4 half-tiles
// per chunk across the 3 gram kernels; 10KB LDS -> high occupancy).
__global__ __launch_bounds__(192) void k_gram_diag(const unsigned short* __restrict__ P,
                                                   const int* __restrict__ off,
                                                   float* __restrict__ G) {
  int l = blockIdx.y;
  long o0 = off[l], o1 = off[l + 1];
  long k0 = o0 + (long)blockIdx.x * 1024;
  if (k0 >= o1) return;
  long rem = o1 - k0;
  int ks = rem > 1024 ? 1024 : (int)rem;     // multiple of 512
  int qh = blockIdx.z;                       // 0: rows 0..127, 1: rows 128..255

  __shared__ unsigned short As[128 * LDA];

  int t = threadIdx.x;
  int wave = t >> 6, lane = t & 63;
  int wr = (wave == 0) ? 0 : 64;
  int wc = (wave == 2) ? 64 : 0;

  f32x4 acc[4][4] = {};

  for (int kk = 0; kk < ks; kk += 32) {
    for (int slot = t; slot < 512; slot += 192) {
      int rr = slot >> 2, gg = slot & 3;
      *(uint4*)&As[rr * LDA + gg * 8] =
          *(const uint4*)&P[(size_t)(qh * 128 + rr) * MPAD + (size_t)(k0 + kk) + gg * 8];
    }
    __syncthreads();
    bf16x8 bfr[4];
#pragma unroll
    for (int fj = 0; fj < 4; ++fj)
      bfr[fj] = *(const bf16x8*)&As[(wc + fj * 16 + (lane & 15)) * LDA + (lane >> 4) * 8];
#pragma unroll
    for (int fi = 0; fi < 4; ++fi) {
      bf16x8 afr = *(const bf16x8*)&As[(wr + fi * 16 + (lane & 15)) * LDA + (lane >> 4) * 8];
#pragma unroll
      for (int fj = 0; fj < 4; ++fj)
        acc[fi][fj] = __builtin_amdgcn_mfma_f32_16x16x32_bf16(afr, bfr[fj], acc[fi][fj], 0, 0, 0);
    }
    __syncthreads();
  }
  float* Gl = G + ((size_t)l << 16);
  int rb = qh * 128 + wr, cb = qh * 128 + wc;
#pragma unroll
  for (int fi = 0; fi < 4; ++fi)
#pragma unroll
    for (int fj = 0; fj < 4; ++fj) {
      int cc = cb + fj * 16 + (lane & 15);
#pragma unroll
      for (int rg = 0; rg < 4; ++rg) {
        int rr = rb + fi * 16 + (lane >> 4) * 4 + rg;
        atomicAdd(&Gl[rr * 256 + cc], acc[fi][fj][rg]);
      }
    }
}

// ---------------- cov: transpose in place + bacc init (style means) ----------
__global__ __launch_bounds__(256) void k_cov(float* __restrict__ G,
                                             const float* __restrict__ sum,
                                             const int* __restrict__ cnt,
                                             float* __restrict__ means,
                                             float* __restrict__ bacc) {
  int bid = blockIdx.x;                       // side*8 + l
  float* A = G + ((size_t)bid << 16);
  int t = threadIdx.x;
  __shared__ float mu[256];
  float fc = (float)cnt[bid];
  float m = sum[bid * 256 + t] / fmaxf(fc, 1.0f);
  mu[t] = m;
  means[bid * 256 + t] = m;
  if (bid >= 8) bacc[(bid - 8) * 256 + t] = m;   // bvec starts at mus
  __syncthreads();
  float rdiv = 1.0f / fmaxf(fmaxf(fc, 1.0f) - 1.0f, 1.0f);
  float mt = mu[t];
  for (int i = t; i < 256; ++i) {
    float g = A[i * 256 + t];
    A[t * 256 + i] = (g - fc * mu[i] * mt) * rdiv;
  }
}

// ---------------- 64-wide panel: two 32-factor+W steps, L21 in registers -----
__global__ __launch_bounds__(256) void k_panel64(float* __restrict__ G,
                                                 float* __restrict__ Wg, int pb) {
  float* LT = G + ((size_t)blockIdx.x << 16);
  int t = threadIdx.x;
  int jb = pb * 64;
  int nT = 224 - jb;                 // rows below the first 32-block
  __shared__ float W1[32 * 36];
  __shared__ float W2[32 * 36];
  __shared__ float Cb[32][33];       // corner L21a rows
  __shared__ float Db[32][33];       // updated corner

  if (t < 64) {
    int l32 = t & 31;
    float x[32];
#pragma unroll
    for (int k = 0; k < 32; ++k)
      x[k] = (k <= l32) ? LT[(size_t)(jb + k) * 256 + jb + l32] : 0.0f;
#pragma unroll
    for (int j = 0; j < 32; ++j) {
      float dj = __shfl(x[j], j, 64);
      float rd = 1.0f / sqrtf(dj);
      float lj = x[j] * rd;
      x[j] = lj;
#pragma unroll
      for (int k = j + 1; k < 32; ++k)
        x[k] -= lj * __shfl(lj, k, 64);
    }
    if (t < 32) {
#pragma unroll
      for (int k = 0; k < 32; ++k)
        if (k <= l32) LT[(size_t)(jb + k) * 256 + jb + l32] = x[k];
    }
    float w[32];
#pragma unroll
    for (int k = 0; k < 32; ++k) w[k] = 0.0f;
#pragma unroll
    for (int i2 = 0; i2 < 32; ++i2) {
      float s = (i2 == l32) ? 1.0f : 0.0f;
#pragma unroll
      for (int k = 0; k < 32; ++k)
        if (k < i2) s -= __shfl(x[k], i2, 64) * w[k];
      float wv = s / __shfl(x[i2], i2, 64);
      w[i2] = (i2 >= l32) ? wv : 0.0f;
    }
    if (t < 32) {
      float* Wgp = Wg + (((size_t)blockIdx.x * 8 + 2 * pb) << 10);
#pragma unroll
      for (int i2 = 0; i2 < 32; ++i2)
        if (i2 >= l32) { W1[i2 * 36 + l32] = w[i2]; Wgp[i2 * 32 + l32] = w[i2]; }
    }
  }
  __syncthreads();

  float xx[32], bb[32];
  if (t < nT) {
    int row = jb + 32 + t;
    float a[32];
#pragma unroll
    for (int k = 0; k < 32; ++k) a[k] = LT[(size_t)(jb + k) * 256 + row];
#pragma unroll
    for (int j = 0; j < 32; ++j) {
      float s = 0.0f;
#pragma unroll
      for (int k = 0; k < 32; ++k)
        if (k <= j) s += a[k] * W1[j * 36 + k];
      xx[j] = s;
      LT[(size_t)(jb + j) * 256 + row] = s;
    }
    if (t < 32) {
#pragma unroll
      for (int j = 0; j < 32; ++j) Cb[t][j] = xx[j];
    }
  }
  __syncthreads();

  if (t < nT) {
    int row = jb + 32 + t;
#pragma unroll
    for (int c = 0; c < 32; ++c) {
      float s = LT[(size_t)(jb + 32 + c) * 256 + row];
#pragma unroll
      for (int k = 0; k < 32; ++k) s -= xx[k] * Cb[c][k];
      bb[c] = s;
    }
    if (t < 32) {
#pragma unroll
      for (int c = 0; c < 32; ++c) Db[t][c] = bb[c];  // only c<=t meaningful
    }
  }
  __syncthreads();

  if (t < 64) {
    int l32 = t & 31;
    float x[32];
#pragma unroll
    for (int k = 0; k < 32; ++k) x[k] = (k <= l32) ? Db[l32][k] : 0.0f;
#pragma unroll
    for (int j = 0; j < 32; ++j) {
      float dj = __shfl(x[j], j, 64);
      float rd = 1.0f / sqrtf(dj);
      float lj = x[j] * rd;
      x[j] = lj;
#pragma unroll
      for (int k = j + 1; k < 32; ++k)
        x[k] -= lj * __shfl(lj, k, 64);
    }
    if (t < 32) {
#pragma unroll
      for (int k = 0; k < 32; ++k)
        if (k <= l32) LT[(size_t)(jb + 32 + k) * 256 + jb + 32 + l32] = x[k];
    }
    float w[32];
#pragma unroll
    for (int k = 0; k < 32; ++k) w[k] = 0.0f;
#pragma unroll
    for (int i2 = 0; i2 < 32; ++i2) {
      float s = (i2 == l32) ? 1.0f : 0.0f;
#pragma unroll
      for (int k = 0; k < 32; ++k)
        if (k < i2) s -= __shfl(x[k], i2, 64) * w[k];
      float wv = s / __shfl(x[i2], i2, 64);
      w[i2] = (i2 >= l32) ? wv : 0.0f;
    }
    if (t < 32) {
      float* Wgp = Wg + (((size_t)blockIdx.x * 8 + 2 * pb + 1) << 10);
#pragma unroll
      for (int i2 = 0; i2 < 32; ++i2)
        if (i2 >= l32) { W2[i2 * 36 + l32] = w[i2]; Wgp[i2 * 32 + l32] = w[i2]; }
    }
  }
  __syncthreads();

  if (t >= 32 && t < nT) {
    int row = jb + 32 + t;
#pragma unroll
    for (int j = 0; j < 32; ++j) {
      float s = 0.0f;
#pragma unroll
      for (int k = 0; k < 32; ++k)
        if (k <= j) s += bb[k] * W2[j * 36 + k];
      LT[(size_t)(jb + 32 + j) * 256 + row] = s;
    }
  }
}

// ---------------- trailing step: A22 -= L21(64) * L21^T (wide, 64x64) --------
__global__ __launch_bounds__(256) void k_trail64(float* __restrict__ G, int pb) {
  int jb = pb * 64;
  int H2 = 192 - jb;
  int nts2 = H2 >> 6;
  int y = blockIdx.y;
  if (y >= (nts2 * (nts2 + 1)) >> 1) return;
  int ti = 0;
  while ((((ti + 1) * (ti + 2)) >> 1) <= y) ++ti;
  int tj = y - ((ti * (ti + 1)) >> 1);
  float* LT = G + ((size_t)blockIdx.x << 16);
  int i0 = jb + 64 + ti * 64, j0 = jb + 64 + tj * 64;

  __shared__ float Li[64][64];
  __shared__ float Lj[64][64];
  int t = threadIdx.x;
  for (int idx = t; idx < 4096; idx += 256) {
    int k = idx >> 6, r = idx & 63;
    Li[k][r] = LT[(size_t)(jb + k) * 256 + i0 + r];
    Lj[k][r] = LT[(size_t)(jb + k) * 256 + j0 + r];
  }
  __syncthreads();

  int tx = t & 15, ty = t >> 4;
  float acc[4][4] = {};
#pragma unroll 4
  for (int k = 0; k < 64; ++k) {
    float4 a = *(const float4*)&Li[k][ty * 4];
    float4 b = *(const float4*)&Lj[k][tx * 4];
    acc[0][0] += a.x * b.x; acc[0][1] += a.x * b.y; acc[0][2] += a.x * b.z; acc[0][3] += a.x * b.w;
    acc[1][0] += a.y * b.x; acc[1][1] += a.y * b.y; acc[1][2] += a.y * b.z; acc[1][3] += a.y * b.w;
    acc[2][0] += a.z * b.x; acc[2][1] += a.z * b.y; acc[2][2] += a.z * b.z; acc[2][3] += a.z * b.w;
    acc[3][0] += a.w * b.x; acc[3][1] += a.w * b.y; acc[3][2] += a.w * b.z; acc[3][3] += a.w * b.w;
  }
#pragma unroll
  for (int jj = 0; jj < 4; ++jj) {
    int j = j0 + tx * 4 + jj;
    float* col = &LT[(size_t)j * 256 + i0 + ty * 4];
#pragma unroll
    for (int ii = 0; ii < 4; ++ii) {
      int i = i0 + ty * 4 + ii;
      if (i >= j) col[ii] -= acc[ii][jj];
    }
  }
}

// ---------------- Vinv level-32 (from Wg; vinit folded in) -------------------
__global__ __launch_bounds__(256) void k_vlevel32w(const float* __restrict__ G,
                                                   const float* __restrict__ Wg,
                                                   float* __restrict__ Vinv) {
  int l = blockIdx.x >> 2, pair = blockIdx.x & 3;
  const float* LT = G + ((size_t)l << 16);
  float* V = Vinv + ((size_t)l << 16);
  const float* W1g = Wg + (((size_t)l * 8 + 2 * pair) << 10);
  const float* W2g = Wg + (((size_t)l * 8 + 2 * pair + 1) << 10);
  int d = pair * 64;
  int t = threadIdx.x;
  __shared__ float A[32][33];
  __shared__ float B[32][33];
  __shared__ float C[32][33];
  for (int idx = t; idx < 1024; idx += 256) {
    int i = idx >> 5, j = idx & 31;
    A[i][j] = LT[(size_t)(d + j) * 256 + d + 32 + i];
    float w1 = (i >= j) ? W1g[idx] : 0.0f;
    B[i][j] = w1;
    V[(size_t)(d + i) * 256 + d + j] = w1;
  }
  __syncthreads();
  for (int idx = t; idx < 1024; idx += 256) {
    int i = idx >> 5, j = idx & 31;
    float s = 0.0f;
#pragma unroll
    for (int k = 0; k < 32; ++k) s += A[i][k] * B[k][j];
    C[i][j] = s;
  }
  __syncthreads();
  for (int idx = t; idx < 1024; idx += 256) {
    int i = idx >> 5, j = idx & 31;
    float w2 = (i >= j) ? W2g[idx] : 0.0f;
    B[i][j] = w2;
    V[(size_t)(d + 32 + i) * 256 + d + 32 + j] = w2;
  }
  __syncthreads();
  for (int idx = t; idx < 1024; idx += 256) {
    int i = idx >> 5, j = idx & 31;
    float s = 0.0f;
#pragma unroll
    for (int k = 0; k < 32; ++k) s += B[i][k] * C[k][j];
    V[(size_t)(d + 32 + i) * 256 + d + j] = -s;
  }
}

// ---------------- triangular inverse doubling: X21 = -W2 * L21 * W1 ----------
template <int N>
__global__ __launch_bounds__(512) void k_vlevel(const float* __restrict__ G,
                                                float* __restrict__ Vinv) {
  constexpr int NP = 256 / (2 * N);
  constexpr int RPT = N / 32;
  constexpr int CPT = N / 16;
  int unit = blockIdx.x;
  int l = unit / NP, pair = unit % NP;
  const float* LT = G + ((size_t)l << 16);
  float* V = Vinv + ((size_t)l << 16);
  int d = pair * 2 * N;
  int t = threadIdx.x;
  int cg = t & 15, rg = t >> 4;
  int r0 = rg * RPT, c0 = cg * CPT;

  __shared__ float Abuf[N][N + 4];
  __shared__ float Bbuf[N][N + 4];

  for (int idx = t; idx < N * N; idx += 512) {
    int k = idx / N, r = idx % N;
    Abuf[r][k] = LT[(size_t)(d + k) * 256 + d + N + r];
  }
  for (int idx = t; idx < N * N; idx += 512) {
    int k = idx / N, c = idx % N;
    Bbuf[k][c] = V[(size_t)(d + k) * 256 + d + c];
  }
  __syncthreads();

  float acc[RPT][CPT];
#pragma unroll
  for (int i = 0; i < RPT; ++i)
#pragma unroll
    for (int j = 0; j < CPT; ++j) acc[i][j] = 0.0f;
  for (int k = 0; k < N; ++k) {
    float av[RPT];
#pragma unroll
    for (int i = 0; i < RPT; ++i) av[i] = Abuf[r0 + i][k];
#pragma unroll
    for (int j = 0; j < CPT; ++j) {
      float bv = Bbuf[k][c0 + j];
#pragma unroll
      for (int i = 0; i < RPT; ++i) acc[i][j] += av[i] * bv;
    }
  }
  __syncthreads();
#pragma unroll
  for (int i = 0; i < RPT; ++i)
#pragma unroll
    for (int j = 0; j < CPT; ++j) Abuf[r0 + i][c0 + j] = acc[i][j];
  for (int idx = t; idx < N * N; idx += 512) {
    int r = idx / N, k = idx % N;
    Bbuf[r][k] = V[(size_t)(d + N + r) * 256 + d + N + k];
  }
  __syncthreads();

#pragma unroll
  for (int i = 0; i < RPT; ++i)
#pragma unroll
    for (int j = 0; j < CPT; ++j) acc[i][j] = 0.0f;
  for (int k = 0; k < N; ++k) {
    float av[RPT];
#pragma unroll
    for (int i = 0; i < RPT; ++i) av[i] = Bbuf[r0 + i][k];
#pragma unroll
    for (int j = 0; j < CPT; ++j) {
      float bv = Abuf[k][c0 + j];
#pragma unroll
      for (int i = 0; i < RPT; ++i) acc[i][j] += av[i] * bv;
    }
  }
#pragma unroll
  for (int i = 0; i < RPT; ++i)
#pragma unroll
    for (int j = 0; j < CPT; ++j)
      V[(size_t)(d + N + r0 + i) * 256 + d + c0 + j] = -acc[i][j];
}

// ---------------- T = Ls * Vinv (tiled f32 GEMM); bacc -= T*muc partials -----
__global__ __launch_bounds__(256) void k_tgemm(const float* __restrict__ G,
                                               const float* __restrict__ Vinv,
                                               const float* __restrict__ means,
                                               const int* __restrict__ valid,
                                               unsigned short* __restrict__ Tb,
                                               float* __restrict__ bacc) {
  int l = blockIdx.y;
  int ti = blockIdx.x >> 2, tj = blockIdx.x & 3;
  unsigned short* Tbl = Tb + ((size_t)l << 16);
  int i0 = ti * 64, j0 = tj * 64;
  int t = threadIdx.x;
  if (!valid[l]) {
    if (tj == 0 && t < 64) bacc[l * 256 + i0 + t] = 0.0f;   // bvec = 0
    for (int idx = t; idx < 4096; idx += 256) {
      int i = idx >> 6, j = idx & 63;
      Tbl[(size_t)(i0 + i) * 256 + j0 + j] = f2bf((i0 + i) == (j0 + j) ? 1.0f : 0.0f);
    }
    return;
  }
  if (tj > ti) {
    for (int idx = t; idx < 4096; idx += 256) {
      int i = idx >> 6, j = idx & 63;
      Tbl[(size_t)(i0 + i) * 256 + j0 + j] = 0;
    }
    return;
  }
  const float* LTs = G + ((size_t)(8 + l) << 16);  // style L, col-major lower
  const float* V = Vinv + ((size_t)l << 16);

  __shared__ float As[64][260];
  __shared__ __align__(16) float Bs[256][68];

  for (int idx = t; idx < 64 * 256; idx += 256) {
    int k = idx >> 6, i = idx & 63;
    As[i][k] = (i0 + i >= k) ? LTs[(size_t)k * 256 + i0 + i] : 0.0f;
  }
  for (int idx = t; idx < 64 * 256; idx += 256) {
    int k = idx >> 6, j = idx & 63;
    Bs[k][j] = V[(size_t)k * 256 + j0 + j];
  }
  __syncthreads();

  int tx = t & 15, ty = t >> 4;
  float acc[4][4] = {};
  int klo = j0, khi = i0 + 64;
  for (int k = klo; k < khi; ++k) {
    float a0 = As[ty * 4 + 0][k], a1 = As[ty * 4 + 1][k];
    float a2 = As[ty * 4 + 2][k], a3 = As[ty * 4 + 3][k];
    float4 b = *(const float4*)&Bs[k][tx * 4];
    acc[0][0] += a0 * b.x; acc[0][1] += a0 * b.y; acc[0][2] += a0 * b.z; acc[0][3] += a0 * b.w;
    acc[1][0] += a1 * b.x; acc[1][1] += a1 * b.y; acc[1][2] += a1 * b.z; acc[1][3] += a1 * b.w;
    acc[2][0] += a2 * b.x; acc[2][1] += a2 * b.y; acc[2][2] += a2 * b.z; acc[2][3] += a2 * b.w;
    acc[3][0] += a3 * b.x; acc[3][1] += a3 * b.y; acc[3][2] += a3 * b.z; acc[3][3] += a3 * b.w;
  }
  float mc[4];
#pragma unroll
  for (int cc = 0; cc < 4; ++cc) mc[cc] = means[l * 256 + j0 + tx * 4 + cc];
#pragma unroll
  for (int rr = 0; rr < 4; ++rr) {
    int i = i0 + ty * 4 + rr;
    float partial = 0.0f;
#pragma unroll
    for (int cc = 0; cc < 4; ++cc) {
      Tbl[(size_t)i * 256 + j0 + tx * 4 + cc] = f2bf(acc[rr][cc]);
      partial += acc[rr][cc] * mc[cc];
    }
    atomicAdd(&bacc[l * 256 + i], -partial);
  }
}

// ---------------- out = T_l * x + b_l (128-px, interleaved row-tiles) --------
__global__ __launch_bounds__(512) void k_outgemm(unsigned short* __restrict__ P,
                                                 const unsigned short* __restrict__ Tb,
                                                 const float* __restrict__ bvec,
                                                 const int* __restrict__ off) {
  long px0 = (long)blockIdx.x * 128;
  if (px0 >= off[8]) return;
  int l = 0;
  while (l < 7 && px0 >= off[l + 1]) ++l;
  const unsigned short* Tl = Tb + ((size_t)l << 16);

  __shared__ unsigned short As[256 * LDA];
  __shared__ unsigned short Bs[128 * LDA];
  __shared__ float bsh[256];

  int t = threadIdx.x, wave = t >> 6, lane = t & 63;
  int wq = wave & 3;                            // row-tile interleave index
  int pq = (wave >> 2) * 64;                    // px half within 128
  if (t < 256) bsh[t] = bvec[l * 256 + t];

  f32x4 acc[4][4] = {};

  for (int kk = 0; kk < 256; kk += 32) {
    {                                           // A: rows kk..255 x 32 k (rest zero)
      int nslots = (256 - kk) * 4;
      for (int slot = t; slot < nslots; slot += 512) {
        int rr = kk + (slot >> 2), gg = slot & 3;
        *(uint4*)&As[rr * LDA + gg * 8] = *(const uint4*)&Tl[rr * 256 + kk + gg * 8];
      }
    }
    {                                           // B: transpose-stage 32k x 128px
      int pg = t & 15, kr = t >> 4;
      uint4 v = *(const uint4*)&P[(size_t)(kk + kr) * MPAD + px0 + pg * 8];
      const unsigned short* vs = (const unsigned short*)&v;
      int krs = kr ^ ((pg & 3) << 3);           // k-block XOR swizzle (bank spread)
#pragma unroll
      for (int e = 0; e < 8; ++e) Bs[(pg * 8 + e) * LDA + krs] = vs[e];
    }
    __syncthreads();
    if ((wq + 12) * 16 + 15 >= kk) {            // any of this wave's tiles live?
      bf16x8 bfr[4];
#pragma unroll
      for (int fj = 0; fj < 4; ++fj) {
        int px = pq + fj * 16 + (lane & 15);
        int gs = (lane >> 4) ^ ((px >> 3) & 3);
        bfr[fj] = *(const bf16x8*)&Bs[px * LDA + gs * 8];
      }
#pragma unroll
      for (int fi = 0; fi < 4; ++fi) {
        int tile = wq + fi * 4;
        if (tile * 16 + 15 >= kk) {
          bf16x8 afr = *(const bf16x8*)&As[(tile * 16 + (lane & 15)) * LDA + (lane >> 4) * 8];
#pragma unroll
          for (int fj = 0; fj < 4; ++fj)
            acc[fi][fj] = __builtin_amdgcn_mfma_f32_16x16x32_bf16(afr, bfr[fj], acc[fi][fj], 0, 0, 0);
        }
      }
    }
    __syncthreads();
  }
#pragma unroll
  for (int fi = 0; fi < 4; ++fi)
#pragma unroll
    for (int fj = 0; fj < 4; ++fj) {
      long p = px0 + pq + fj * 16 + (lane & 15);
#pragma unroll
      for (int rg = 0; rg < 4; ++rg) {
        int rr = (wq + fi * 4) * 16 + (lane >> 4) * 4 + rg;
        float v = acc[fi][fj][rg] + bsh[rr];
        P[(size_t)rr * MPAD + p] = f2bf(v);
      }
    }
}

// =============================================================================
extern "C" void kernel_launch(void* const* d_in, const int* in_sizes, int n_in,
                              void* d_out, int out_size, void* d_ws, size_t ws_size,
                              hipStream_t stream) {
  const float* cfeat = (const float*)d_in[0];
  const float* sfeat = (const float*)d_in[1];
  const int* seg_c   = (const int*)d_in[2];
  const int* seg_s   = (const int*)d_in[3];

  char* ws = (char*)d_ws;
  size_t o = 0;
  auto take = [&](size_t b) { size_t r = o; o += (b + 255) & ~(size_t)255; return r; };

  unsigned short* P  = (unsigned short*)(ws + take((size_t)NCH * MPAD * 2));
  size_t zero_b = o;
  float* G           = (float*)(ws + take((size_t)2 * 8 * 65536 * 4));
  float* Vinv        = (float*)(ws + take((size_t)8 * 65536 * 4));
  float* sum         = (float*)(ws + take((size_t)2 * 8 * 256 * 4));
  float* bacc        = (float*)(ws + take((size_t)8 * 256 * 4));
  int*   hist        = (int*)(ws + take((size_t)2 * 128 * 8 * 4));
  size_t zero_e = o;
  unsigned short* Tb = (unsigned short*)(ws + take((size_t)8 * 65536 * 2));
  float* Wg          = (float*)(ws + take((size_t)16 * 8 * 1024 * 4));
  int*   dst         = (int*)(ws + take((size_t)2 * M_PIX * 4));
  float* means       = (float*)(ws + take((size_t)2 * 8 * 256 * 4));
  int*   base        = (int*)(ws + take((size_t)2 * 128 * 8 * 4));
  int*   off         = (int*)(ws + take((size_t)2 * 9 * 4));
  int*   cnt         = (int*)(ws + take((size_t)2 * 8 * 4));
  int*   valid       = (int*)(ws + take((size_t)8 * 4));
  (void)ws_size; (void)n_in; (void)in_sizes; (void)out_size;

  hipMemsetAsync(ws + zero_b, 0, zero_e - zero_b, stream);

  k_hist<<<dim3(128), dim3(256), 0, stream>>>(seg_c, seg_s, hist);
  k_scan<<<dim3(1), dim3(256), 0, stream>>>(hist, base, off, cnt, valid);
  k_rank<<<dim3(128), dim3(256), 0, stream>>>(seg_c, seg_s, base, dst);

  // style (side 1) first, then content (side 0); P is reused, stream-serial.
  for (int s = 1; s >= 0; --s) {
    const float* feat = s ? sfeat : cfeat;
    const int* seg = s ? seg_s : seg_c;
    k_padzero<<<dim3(8, 16), dim3(256), 0, stream>>>(P, off + s * 9, cnt + s * 8);
    k_pack<<<dim3(128, 8), dim3(256), 0, stream>>>(feat, seg, dst + (size_t)s * M_PIX,
                                                   base + s * 1024, P);
    k_gram_off<<<dim3(260, 8), dim3(256), 0, stream>>>(P, off + s * 9,
                                                       G + (size_t)s * 8 * 65536,
                                                       sum + (size_t)s * 8 * 256);
    k_gram_diag<<<dim3(260, 8, 2), dim3(192), 0, stream>>>(P, off + s * 9,
                                                           G + (size_t)s * 8 * 65536);
  }

  k_cov<<<dim3(16), dim3(256), 0, stream>>>(G, sum, cnt, means, bacc);
  for (int pb = 0; pb < 4; ++pb) {
    k_panel64<<<dim3(16), dim3(256), 0, stream>>>(G, Wg, pb);
    if (pb < 3) {
      int nts2 = (192 - 64 * pb) >> 6;
      k_trail64<<<dim3(16, (nts2 * (nts2 + 1)) >> 1), dim3(256), 0, stream>>>(G, pb);
    }
  }
  k_vlevel32w<<<dim3(32), dim3(256), 0, stream>>>(G, Wg, Vinv);
  k_vlevel<64><<<dim3(16), dim3(512), 0, stream>>>(G, Vinv);
  k_vlevel<128><<<dim3(8), dim3(512), 0, stream>>>(G, Vinv);
  k_tgemm<<<dim3(16, 8), dim3(256), 0, stream>>>(G, Vinv, means, valid, Tb, bacc);
  k_outgemm<<<dim3(2080), dim3(512), 0, stream>>>(P, Tb, bacc, off);
  k_unpack<<<dim3(128, 8), dim3(256), 0, stream>>>(P, seg_c, dst, base, (float*)d_out);
}

// Round 19
// 983.426 us; speedup vs baseline: 1.0756x; 1.0756x over previous
//
#include <hip/hip_runtime.h>

#define NCH   256
#define M_PIX 262144
#define MPAD  266240   // 520*512 ; >= M_PIX + 8*512 worst-case alignment pad
#define LDA   40       // padded LDS leading dim (bf16 elements) for 32-wide k tiles

typedef short bf16x8 __attribute__((ext_vector_type(8)));
typedef float f32x4  __attribute__((ext_vector_type(4)));

__device__ __forceinline__ unsigned short f2bf(float f) {
  union { float f; unsigned u; } v; v.f = f;
  unsigned r = v.u + 0x7FFFu + ((v.u >> 16) & 1u);
  return (unsigned short)(r >> 16);
}
__device__ __forceinline__ float bf2f(unsigned short h) {
  union { unsigned u; float f; } v; v.u = ((unsigned)h) << 16;
  return v.f;
}

// ---------------- histogram: per-2048-pixel-block label counts, both segs ----
__global__ __launch_bounds__(256) void k_hist(const int* __restrict__ seg_c,
                                              const int* __restrict__ seg_s,
                                              int* __restrict__ hist) {
  __shared__ int h[16];
  int t = threadIdx.x;
  if (t < 16) h[t] = 0;
  __syncthreads();
  int p0 = blockIdx.x * 2048 + t * 8;
#pragma unroll
  for (int e = 0; e < 8; ++e) {
    atomicAdd(&h[seg_c[p0 + e] & 7], 1);
    atomicAdd(&h[8 + (seg_s[p0 + e] & 7)], 1);
  }
  __syncthreads();
  if (t < 8) hist[blockIdx.x * 8 + t] = h[t];
  else if (t < 16) hist[1024 + blockIdx.x * 8 + (t - 8)] = h[t];
}

// ---------------- scan: totals, 512-aligned offsets, per-block bases, valid --
__global__ __launch_bounds__(256) void k_scan(const int* __restrict__ hist,
                                              int* __restrict__ base,
                                              int* __restrict__ off,
                                              int* __restrict__ cnt,
                                              int* __restrict__ valid) {
  __shared__ int lh[2048];
  __shared__ int tot[16];
  __shared__ int loff[2][9];
  int t = threadIdx.x;
  for (int i = t; i < 2048; i += 256) lh[i] = hist[i];
  __syncthreads();
  if (t < 16) {
    int s = t >> 3, l = t & 7, acc = 0;
    for (int b = 0; b < 128; ++b) acc += lh[s * 1024 + b * 8 + l];
    tot[t] = acc;
  }
  __syncthreads();
  if (t < 2) {
    int run = 0;
    for (int l = 0; l < 8; ++l) {
      loff[t][l] = run;
      run = (run + tot[t * 8 + l] + 511) & ~511;
    }
    loff[t][8] = run;
    for (int l = 0; l < 9; ++l) off[t * 9 + l] = loff[t][l];
    for (int l = 0; l < 8; ++l) cnt[t * 8 + l] = tot[t * 8 + l];
  }
  __syncthreads();
  if (t < 8) {
    long nc = tot[t], ns = tot[8 + t];
    valid[t] = (nc > 10 && ns > 10 && nc < 100 * ns && ns < 100 * nc) ? 1 : 0;
  }
  if (t < 16) {
    int s = t >> 3, l = t & 7;
    int run = loff[s][l];
    for (int b = 0; b < 128; ++b) {
      base[s * 1024 + b * 8 + l] = run;
      run += lh[s * 1024 + b * 8 + l];
    }
  }
}

// ---------------- rank: stable per-pixel destination slot (counting sort) ----
__global__ __launch_bounds__(256) void k_rank(const int* __restrict__ seg_c,
                                              const int* __restrict__ seg_s,
                                              const int* __restrict__ base,
                                              int* __restrict__ dst) {
  __shared__ int sc[8 * 272];
  __shared__ int rb[256 * 8];
  __shared__ int bb[8];
  int t = threadIdx.x;
  for (int s = 0; s < 2; ++s) {
    const int* seg = s ? seg_s : seg_c;
    const int* bas = base + s * 1024 + blockIdx.x * 8;
    int* dd = dst + (size_t)s * M_PIX;
    int p0 = blockIdx.x * 2048 + t * 8;
    unsigned pk2 = 0, cpk = 0;
#pragma unroll
    for (int e = 0; e < 8; ++e) {
      int lb = seg[p0 + e] & 7;
      pk2 |= (unsigned)lb << (3 * e);
      cpk += 1u << (4 * lb);
    }
#pragma unroll
    for (int lq = 0; lq < 8; ++lq) sc[lq * 272 + t] = (int)((cpk >> (4 * lq)) & 15u);
    if (t < 8) bb[t] = bas[t];
    __syncthreads();
    for (int d = 1; d < 256; d <<= 1) {
      int v[8];
#pragma unroll
      for (int lq = 0; lq < 8; ++lq)
        v[lq] = sc[lq * 272 + t] + ((t >= d) ? sc[lq * 272 + t - d] : 0);
      __syncthreads();
#pragma unroll
      for (int lq = 0; lq < 8; ++lq) sc[lq * 272 + t] = v[lq];
      __syncthreads();
    }
#pragma unroll
    for (int lq = 0; lq < 8; ++lq)
      rb[t * 8 + lq] = bb[lq] + sc[lq * 272 + t] - (int)((cpk >> (4 * lq)) & 15u);
#pragma unroll
    for (int e = 0; e < 8; ++e) {
      int lb = (int)((pk2 >> (3 * e)) & 7u);
      int dpos = rb[t * 8 + lb]++;
      dd[p0 + e] = dpos;
    }
    __syncthreads();
  }
}

// ---------------- zero the alignment pads of P (within-label pads only) ------
__global__ __launch_bounds__(256) void k_padzero(unsigned short* __restrict__ P,
                                                 const int* __restrict__ off,
                                                 const int* __restrict__ cnt) {
  int l = blockIdx.x;
  int c0 = off[l] + cnt[l], c1 = off[l + 1];
  int w = c1 - c0;
  if (w <= 0) return;
  int r0 = blockIdx.y * 16;
  for (int r = r0; r < r0 + 16; ++r)
    for (int cc = threadIdx.x; cc < w; cc += 256)
      P[(size_t)r * MPAD + c0 + cc] = 0;
}

// ---------------- pack: coalesced-both-sides via LDS local sort --------------
__global__ __launch_bounds__(256) void k_pack(const float* __restrict__ feat,
                                              const int* __restrict__ seg,
                                              const int* __restrict__ dst,
                                              const int* __restrict__ base,
                                              unsigned short* __restrict__ P) {
  int b = blockIdx.x, g = blockIdx.y, t = threadIdx.x;
  int p0 = b * 2048;
  __shared__ unsigned short buf[8][2048];
  __shared__ int h[8], lbase[9], gbase[8];
  if (t < 8) { h[t] = 0; gbase[t] = base[b * 8 + t]; }
  __syncthreads();
  int lbr[2][4], slotr[2][4], gd[8];
#pragma unroll
  for (int j = 0; j < 2; ++j) {
    int4 sg = *(const int4*)&seg[p0 + j * 1024 + t * 4];
    lbr[j][0] = sg.x & 7; lbr[j][1] = sg.y & 7;
    lbr[j][2] = sg.z & 7; lbr[j][3] = sg.w & 7;
#pragma unroll
    for (int e = 0; e < 4; ++e) atomicAdd(&h[lbr[j][e]], 1);
  }
  __syncthreads();
  if (t == 0) {
    int run = 0;
    for (int l = 0; l < 8; ++l) { lbase[l] = run; run += h[l]; }
    lbase[8] = run;
  }
  __syncthreads();
#pragma unroll
  for (int j = 0; j < 2; ++j) {
    int4 dv = *(const int4*)&dst[p0 + j * 1024 + t * 4];
    slotr[j][0] = lbase[lbr[j][0]] + (dv.x - gbase[lbr[j][0]]);
    slotr[j][1] = lbase[lbr[j][1]] + (dv.y - gbase[lbr[j][1]]);
    slotr[j][2] = lbase[lbr[j][2]] + (dv.z - gbase[lbr[j][2]]);
    slotr[j][3] = lbase[lbr[j][3]] + (dv.w - gbase[lbr[j][3]]);
  }
#pragma unroll
  for (int i = 0; i < 8; ++i) {
    int q = i * 256 + t;
    int l = 0;
    while (l < 7 && q >= lbase[l + 1]) ++l;
    gd[i] = gbase[l] + q - lbase[l];
  }
  int n0 = g * 32;
#pragma unroll 1
  for (int cp = 0; cp < 4; ++cp) {
#pragma unroll
    for (int c = 0; c < 8; ++c) {
      const float* fp = &feat[(size_t)(n0 + cp * 8 + c) * M_PIX + p0];
      float4 v0 = *(const float4*)&fp[t * 4];
      float4 v1 = *(const float4*)&fp[1024 + t * 4];
      buf[c][slotr[0][0]] = f2bf(v0.x); buf[c][slotr[0][1]] = f2bf(v0.y);
      buf[c][slotr[0][2]] = f2bf(v0.z); buf[c][slotr[0][3]] = f2bf(v0.w);
      buf[c][slotr[1][0]] = f2bf(v1.x); buf[c][slotr[1][1]] = f2bf(v1.y);
      buf[c][slotr[1][2]] = f2bf(v1.z); buf[c][slotr[1][3]] = f2bf(v1.w);
    }
    __syncthreads();
#pragma unroll
    for (int c = 0; c < 8; ++c) {
      unsigned short* pp = &P[(size_t)(n0 + cp * 8 + c) * MPAD];
#pragma unroll
      for (int i = 0; i < 8; ++i)
        pp[gd[i]] = buf[c][i * 256 + t];
    }
    __syncthreads();
  }
}

// ---------------- unpack: mirrored (contiguous P reads, float4 out stores) ---
__global__ __launch_bounds__(256) void k_unpack(const unsigned short* __restrict__ P,
                                                const int* __restrict__ seg,
                                                const int* __restrict__ dst,
                                                const int* __restrict__ base,
                                                float* __restrict__ out) {
  int b = blockIdx.x, g = blockIdx.y, t = threadIdx.x;
  int p0 = b * 2048;
  __shared__ unsigned short buf[8][2048];
  __shared__ int h[8], lbase[9], gbase[8];
  if (t < 8) { h[t] = 0; gbase[t] = base[b * 8 + t]; }
  __syncthreads();
  int lbr[2][4], slotr[2][4], gd[8];
#pragma unroll
  for (int j = 0; j < 2; ++j) {
    int4 sg = *(const int4*)&seg[p0 + j * 1024 + t * 4];
    lbr[j][0] = sg.x & 7; lbr[j][1] = sg.y & 7;
    lbr[j][2] = sg.z & 7; lbr[j][3] = sg.w & 7;
#pragma unroll
    for (int e = 0; e < 4; ++e) atomicAdd(&h[lbr[j][e]], 1);
  }
  __syncthreads();
  if (t == 0) {
    int run = 0;
    for (int l = 0; l < 8; ++l) { lbase[l] = run; run += h[l]; }
    lbase[8] = run;
  }
  __syncthreads();
#pragma unroll
  for (int j = 0; j < 2; ++j) {
    int4 dv = *(const int4*)&dst[p0 + j * 1024 + t * 4];
    slotr[j][0] = lbase[lbr[j][0]] + (dv.x - gbase[lbr[j][0]]);
    slotr[j][1] = lbase[lbr[j][1]] + (dv.y - gbase[lbr[j][1]]);
    slotr[j][2] = lbase[lbr[j][2]] + (dv.z - gbase[lbr[j][2]]);
    slotr[j][3] = lbase[lbr[j][3]] + (dv.w - gbase[lbr[j][3]]);
  }
#pragma unroll
  for (int i = 0; i < 8; ++i) {
    int q = i * 256 + t;
    int l = 0;
    while (l < 7 && q >= lbase[l + 1]) ++l;
    gd[i] = gbase[l] + q - lbase[l];
  }
  int n0 = g * 32;
#pragma unroll 1
  for (int cp = 0; cp < 4; ++cp) {
#pragma unroll
    for (int c = 0; c < 8; ++c) {
      const unsigned short* pp = &P[(size_t)(n0 + cp * 8 + c) * MPAD];
#pragma unroll
      for (int i = 0; i < 8; ++i)
        buf[c][i * 256 + t] = pp[gd[i]];
    }
    __syncthreads();
#pragma unroll
    for (int c = 0; c < 8; ++c) {
      float* op = &out[(size_t)(n0 + cp * 8 + c) * M_PIX + p0];
      float4 v0, v1;
      v0.x = bf2f(buf[c][slotr[0][0]]); v0.y = bf2f(buf[c][slotr[0][1]]);
      v0.z = bf2f(buf[c][slotr[0][2]]); v0.w = bf2f(buf[c][slotr[0][3]]);
      v1.x = bf2f(buf[c][slotr[1][0]]); v1.y = bf2f(buf[c][slotr[1][1]]);
      v1.z = bf2f(buf[c][slotr[1][2]]); v1.w = bf2f(buf[c][slotr[1][3]]);
      *(float4*)&op[t * 4] = v0;
      *(float4*)&op[1024 + t * 4] = v1;
    }
    __syncthreads();
  }
}

// ---------------- Gram: quadrant blocks, 1024-k chunks (halved atomics) ------
__global__ __launch_bounds__(256) void k_gram(const unsigned short* __restrict__ P,
                                              const int* __restrict__ off,
                                              float* __restrict__ G,
                                              float* __restrict__ sum) {
  int l = blockIdx.y;
  long o0 = off[l], o1 = off[l + 1];
  long k0 = o0 + (long)blockIdx.x * 1024;
  if (k0 >= o1) return;
  long rem = o1 - k0;
  int ks = rem > 1024 ? 1024 : (int)rem;     // multiple of 512
  int qz = blockIdx.z;
  int qi = (qz == 0) ? 0 : 1;
  int qj = (qz == 2) ? 1 : 0;

  __shared__ unsigned short As[128 * LDA];
  __shared__ unsigned short Bs[128 * LDA];

  int t = threadIdx.x;
  int wave = t >> 6, lane = t & 63;
  int wr = (wave >> 1) * 64, wc = (wave & 1) * 64;

  f32x4 acc[4][4] = {};
  float rsum = 0.0f;

  for (int kk = 0; kk < ks; kk += 32) {
#pragma unroll
    for (int it = 0; it < 2; ++it) {
      int slot = t + it * 256;
      int rr = slot >> 2, gg = slot & 3;
      *(uint4*)&As[rr * LDA + gg * 8] =
          *(const uint4*)&P[(size_t)(qi * 128 + rr) * MPAD + (size_t)(k0 + kk) + gg * 8];
      *(uint4*)&Bs[rr * LDA + gg * 8] =
          *(const uint4*)&P[(size_t)(qj * 128 + rr) * MPAD + (size_t)(k0 + kk) + gg * 8];
    }
    __syncthreads();
    if (qz == 1) {                            // fused psum: As=rows 128.., Bs=rows 0..
      const unsigned short* src = (t < 128) ? &As[t * LDA] : &Bs[(t - 128) * LDA];
#pragma unroll
      for (int e = 0; e < 16; ++e) {
        unsigned v = *(const unsigned*)&src[e * 2];
        rsum += bf2f((unsigned short)(v & 0xFFFFu)) + bf2f((unsigned short)(v >> 16));
      }
    }
    bf16x8 bfr[4];
#pragma unroll
    for (int fj = 0; fj < 4; ++fj)
      bfr[fj] = *(const bf16x8*)&Bs[(wc + fj * 16 + (lane & 15)) * LDA + (lane >> 4) * 8];
#pragma unroll
    for (int fi = 0; fi < 4; ++fi) {
      bf16x8 afr = *(const bf16x8*)&As[(wr + fi * 16 + (lane & 15)) * LDA + (lane >> 4) * 8];
#pragma unroll
      for (int fj = 0; fj < 4; ++fj)
        acc[fi][fj] = __builtin_amdgcn_mfma_f32_16x16x32_bf16(afr, bfr[fj], acc[fi][fj], 0, 0, 0);
    }
    __syncthreads();
  }
  float* Gl = G + ((size_t)l << 16);
  int rb = qi * 128 + wr, cb = qj * 128 + wc;
#pragma unroll
  for (int fi = 0; fi < 4; ++fi)
#pragma unroll
    for (int fj = 0; fj < 4; ++fj) {
      int cc = cb + fj * 16 + (lane & 15);
#pragma unroll
      for (int rg = 0; rg < 4; ++rg) {
        int rr = rb + fi * 16 + (lane >> 4) * 4 + rg;
        atomicAdd(&Gl[rr * 256 + cc], acc[fi][fj][rg]);
      }
    }
  if (qz == 1) {
    int row = (t < 128) ? (128 + t) : (t - 128);
    atomicAdd(&sum[l * 256 + row], rsum);
  }
}

// ---------------- cov: transpose in place + bacc init (style means) ----------
__global__ __launch_bounds__(256) void k_cov(float* __restrict__ G,
                                             const float* __restrict__ sum,
                                             const int* __restrict__ cnt,
                                             float* __restrict__ means,
                                             float* __restrict__ bacc) {
  int bid = blockIdx.x;                       // side*8 + l
  float* A = G + ((size_t)bid << 16);
  int t = threadIdx.x;
  __shared__ float mu[256];
  float fc = (float)cnt[bid];
  float m = sum[bid * 256 + t] / fmaxf(fc, 1.0f);
  mu[t] = m;
  means[bid * 256 + t] = m;
  if (bid >= 8) bacc[(bid - 8) * 256 + t] = m;   // bvec starts at mus
  __syncthreads();
  float rdiv = 1.0f / fmaxf(fmaxf(fc, 1.0f) - 1.0f, 1.0f);
  float mt = mu[t];
  for (int i = t; i < 256; ++i) {
    float g = A[i * 256 + t];
    A[t * 256 + i] = (g - fc * mu[i] * mt) * rdiv;
  }
}

// ---------------- 64-wide panel: two 32-factor+W steps, L21 in registers -----
__global__ __launch_bounds__(256) void k_panel64(float* __restrict__ G,
                                                 float* __restrict__ Wg, int pb) {
  float* LT = G + ((size_t)blockIdx.x << 16);
  int t = threadIdx.x;
  int jb = pb * 64;
  int nT = 224 - jb;                 // rows below the first 32-block
  __shared__ float W1[32 * 36];
  __shared__ float W2[32 * 36];
  __shared__ float Cb[32][33];       // corner L21a rows
  __shared__ float Db[32][33];       // updated corner

  if (t < 64) {
    int l32 = t & 31;
    float x[32];
#pragma unroll
    for (int k = 0; k < 32; ++k)
      x[k] = (k <= l32) ? LT[(size_t)(jb + k) * 256 + jb + l32] : 0.0f;
#pragma unroll
    for (int j = 0; j < 32; ++j) {
      float dj = __shfl(x[j], j, 64);
      float rd = 1.0f / sqrtf(dj);
      float lj = x[j] * rd;
      x[j] = lj;
#pragma unroll
      for (int k = j + 1; k < 32; ++k)
        x[k] -= lj * __shfl(lj, k, 64);
    }
    if (t < 32) {
#pragma unroll
      for (int k = 0; k < 32; ++k)
        if (k <= l32) LT[(size_t)(jb + k) * 256 + jb + l32] = x[k];
    }
    float w[32];
#pragma unroll
    for (int k = 0; k < 32; ++k) w[k] = 0.0f;
#pragma unroll
    for (int i2 = 0; i2 < 32; ++i2) {
      float s = (i2 == l32) ? 1.0f : 0.0f;
#pragma unroll
      for (int k = 0; k < 32; ++k)
        if (k < i2) s -= __shfl(x[k], i2, 64) * w[k];
      float wv = s / __shfl(x[i2], i2, 64);
      w[i2] = (i2 >= l32) ? wv : 0.0f;
    }
    if (t < 32) {
      float* Wgp = Wg + (((size_t)blockIdx.x * 8 + 2 * pb) << 10);
#pragma unroll
      for (int i2 = 0; i2 < 32; ++i2)
        if (i2 >= l32) { W1[i2 * 36 + l32] = w[i2]; Wgp[i2 * 32 + l32] = w[i2]; }
    }
  }
  __syncthreads();

  float xx[32], bb[32];
  if (t < nT) {
    int row = jb + 32 + t;
    float a[32];
#pragma unroll
    for (int k = 0; k < 32; ++k) a[k] = LT[(size_t)(jb + k) * 256 + row];
#pragma unroll
    for (int j = 0; j < 32; ++j) {
      float s = 0.0f;
#pragma unroll
      for (int k = 0; k < 32; ++k)
        if (k <= j) s += a[k] * W1[j * 36 + k];
      xx[j] = s;
      LT[(size_t)(jb + j) * 256 + row] = s;
    }
    if (t < 32) {
#pragma unroll
      for (int j = 0; j < 32; ++j) Cb[t][j] = xx[j];
    }
  }
  __syncthreads();

  if (t < nT) {
    int row = jb + 32 + t;
#pragma unroll
    for (int c = 0; c < 32; ++c) {
      float s = LT[(size_t)(jb + 32 + c) * 256 + row];
#pragma unroll
      for (int k = 0; k < 32; ++k) s -= xx[k] * Cb[c][k];
      bb[c] = s;
    }
    if (t < 32) {
#pragma unroll
      for (int c = 0; c < 32; ++c) Db[t][c] = bb[c];  // only c<=t meaningful
    }
  }
  __syncthreads();

  if (t < 64) {
    int l32 = t & 31;
    float x[32];
#pragma unroll
    for (int k = 0; k < 32; ++k) x[k] = (k <= l32) ? Db[l32][k] : 0.0f;
#pragma unroll
    for (int j = 0; j < 32; ++j) {
      float dj = __shfl(x[j], j, 64);
      float rd = 1.0f / sqrtf(dj);
      float lj = x[j] * rd;
      x[j] = lj;
#pragma unroll
      for (int k = j + 1; k < 32; ++k)
        x[k] -= lj * __shfl(lj, k, 64);
    }
    if (t < 32) {
#pragma unroll
      for (int k = 0; k < 32; ++k)
        if (k <= l32) LT[(size_t)(jb + 32 + k) * 256 + jb + 32 + l32] = x[k];
    }
    float w[32];
#pragma unroll
    for (int k = 0; k < 32; ++k) w[k] = 0.0f;
#pragma unroll
    for (int i2 = 0; i2 < 32; ++i2) {
      float s = (i2 == l32) ? 1.0f : 0.0f;
#pragma unroll
      for (int k = 0; k < 32; ++k)
        if (k < i2) s -= __shfl(x[k], i2, 64) * w[k];
      float wv = s / __shfl(x[i2], i2, 64);
      w[i2] = (i2 >= l32) ? wv : 0.0f;
    }
    if (t < 32) {
      float* Wgp = Wg + (((size_t)blockIdx.x * 8 + 2 * pb + 1) << 10);
#pragma unroll
      for (int i2 = 0; i2 < 32; ++i2)
        if (i2 >= l32) { W2[i2 * 36 + l32] = w[i2]; Wgp[i2 * 32 + l32] = w[i2]; }
    }
  }
  __syncthreads();

  if (t >= 32 && t < nT) {
    int row = jb + 32 + t;
#pragma unroll
    for (int j = 0; j < 32; ++j) {
      float s = 0.0f;
#pragma unroll
      for (int k = 0; k < 32; ++k)
        if (k <= j) s += bb[k] * W2[j * 36 + k];
      LT[(size_t)(jb + 32 + j) * 256 + row] = s;
    }
  }
}

// ---------------- trailing step: A22 -= L21(64) * L21^T (wide, 64x64) --------
__global__ __launch_bounds__(256) void k_trail64(float* __restrict__ G, int pb) {
  int jb = pb * 64;
  int H2 = 192 - jb;
  int nts2 = H2 >> 6;
  int y = blockIdx.y;
  if (y >= (nts2 * (nts2 + 1)) >> 1) return;
  int ti = 0;
  while ((((ti + 1) * (ti + 2)) >> 1) <= y) ++ti;
  int tj = y - ((ti * (ti + 1)) >> 1);
  float* LT = G + ((size_t)blockIdx.x << 16);
  int i0 = jb + 64 + ti * 64, j0 = jb + 64 + tj * 64;

  __shared__ float Li[64][64];
  __shared__ float Lj[64][64];
  int t = threadIdx.x;
  for (int idx = t; idx < 4096; idx += 256) {
    int k = idx >> 6, r = idx & 63;
    Li[k][r] = LT[(size_t)(jb + k) * 256 + i0 + r];
    Lj[k][r] = LT[(size_t)(jb + k) * 256 + j0 + r];
  }
  __syncthreads();

  int tx = t & 15, ty = t >> 4;
  float acc[4][4] = {};
#pragma unroll 4
  for (int k = 0; k < 64; ++k) {
    float4 a = *(const float4*)&Li[k][ty * 4];
    float4 b = *(const float4*)&Lj[k][tx * 4];
    acc[0][0] += a.x * b.x; acc[0][1] += a.x * b.y; acc[0][2] += a.x * b.z; acc[0][3] += a.x * b.w;
    acc[1][0] += a.y * b.x; acc[1][1] += a.y * b.y; acc[1][2] += a.y * b.z; acc[1][3] += a.y * b.w;
    acc[2][0] += a.z * b.x; acc[2][1] += a.z * b.y; acc[2][2] += a.z * b.z; acc[2][3] += a.z * b.w;
    acc[3][0] += a.w * b.x; acc[3][1] += a.w * b.y; acc[3][2] += a.w * b.z; acc[3][3] += a.w * b.w;
  }
#pragma unroll
  for (int jj = 0; jj < 4; ++jj) {
    int j = j0 + tx * 4 + jj;
    float* col = &LT[(size_t)j * 256 + i0 + ty * 4];
#pragma unroll
    for (int ii = 0; ii < 4; ++ii) {
      int i = i0 + ty * 4 + ii;
      if (i >= j) col[ii] -= acc[ii][jj];
    }
  }
}

// ---------------- Vinv level-32 (from Wg; vinit folded in) -------------------
__global__ __launch_bounds__(256) void k_vlevel32w(const float* __restrict__ G,
                                                   const float* __restrict__ Wg,
                                                   float* __restrict__ Vinv) {
  int l = blockIdx.x >> 2, pair = blockIdx.x & 3;
  const float* LT = G + ((size_t)l << 16);
  float* V = Vinv + ((size_t)l << 16);
  const float* W1g = Wg + (((size_t)l * 8 + 2 * pair) << 10);
  const float* W2g = Wg + (((size_t)l * 8 + 2 * pair + 1) << 10);
  int d = pair * 64;
  int t = threadIdx.x;
  __shared__ float A[32][33];
  __shared__ float B[32][33];
  __shared__ float C[32][33];
  for (int idx = t; idx < 1024; idx += 256) {
    int i = idx >> 5, j = idx & 31;
    A[i][j] = LT[(size_t)(d + j) * 256 + d + 32 + i];
    float w1 = (i >= j) ? W1g[idx] : 0.0f;
    B[i][j] = w1;
    V[(size_t)(d + i) * 256 + d + j] = w1;
  }
  __syncthreads();
  for (int idx = t; idx < 1024; idx += 256) {
    int i = idx >> 5, j = idx & 31;
    float s = 0.0f;
#pragma unroll
    for (int k = 0; k < 32; ++k) s += A[i][k] * B[k][j];
    C[i][j] = s;
  }
  __syncthreads();
  for (int idx = t; idx < 1024; idx += 256) {
    int i = idx >> 5, j = idx & 31;
    float w2 = (i >= j) ? W2g[idx] : 0.0f;
    B[i][j] = w2;
    V[(size_t)(d + 32 + i) * 256 + d + 32 + j] = w2;
  }
  __syncthreads();
  for (int idx = t; idx < 1024; idx += 256) {
    int i = idx >> 5, j = idx & 31;
    float s = 0.0f;
#pragma unroll
    for (int k = 0; k < 32; ++k) s += B[i][k] * C[k][j];
    V[(size_t)(d + 32 + i) * 256 + d + j] = -s;
  }
}

// ---------------- triangular inverse doubling: X21 = -W2 * L21 * W1 ----------
template <int N>
__global__ __launch_bounds__(512) void k_vlevel(const float* __restrict__ G,
                                                float* __restrict__ Vinv) {
  constexpr int NP = 256 / (2 * N);
  constexpr int RPT = N / 32;
  constexpr int CPT = N / 16;
  int unit = blockIdx.x;
  int l = unit / NP, pair = unit % NP;
  const float* LT = G + ((size_t)l << 16);
  float* V = Vinv + ((size_t)l << 16);
  int d = pair * 2 * N;
  int t = threadIdx.x;
  int cg = t & 15, rg = t >> 4;
  int r0 = rg * RPT, c0 = cg * CPT;

  __shared__ float Abuf[N][N + 4];
  __shared__ float Bbuf[N][N + 4];

  for (int idx = t; idx < N * N; idx += 512) {
    int k = idx / N, r = idx % N;
    Abuf[r][k] = LT[(size_t)(d + k) * 256 + d + N + r];
  }
  for (int idx = t; idx < N * N; idx += 512) {
    int k = idx / N, c = idx % N;
    Bbuf[k][c] = V[(size_t)(d + k) * 256 + d + c];
  }
  __syncthreads();

  float acc[RPT][CPT];
#pragma unroll
  for (int i = 0; i < RPT; ++i)
#pragma unroll
    for (int j = 0; j < CPT; ++j) acc[i][j] = 0.0f;
  for (int k = 0; k < N; ++k) {
    float av[RPT];
#pragma unroll
    for (int i = 0; i < RPT; ++i) av[i] = Abuf[r0 + i][k];
#pragma unroll
    for (int j = 0; j < CPT; ++j) {
      float bv = Bbuf[k][c0 + j];
#pragma unroll
      for (int i = 0; i < RPT; ++i) acc[i][j] += av[i] * bv;
    }
  }
  __syncthreads();
#pragma unroll
  for (int i = 0; i < RPT; ++i)
#pragma unroll
    for (int j = 0; j < CPT; ++j) Abuf[r0 + i][c0 + j] = acc[i][j];
  for (int idx = t; idx < N * N; idx += 512) {
    int r = idx / N, k = idx % N;
    Bbuf[r][k] = V[(size_t)(d + N + r) * 256 + d + N + k];
  }
  __syncthreads();

#pragma unroll
  for (int i = 0; i < RPT; ++i)
#pragma unroll
    for (int j = 0; j < CPT; ++j) acc[i][j] = 0.0f;
  for (int k = 0; k < N; ++k) {
    float av[RPT];
#pragma unroll
    for (int i = 0; i < RPT; ++i) av[i] = Bbuf[r0 + i][k];
#pragma unroll
    for (int j = 0; j < CPT; ++j) {
      float bv = Abuf[k][c0 + j];
#pragma unroll
      for (int i = 0; i < RPT; ++i) acc[i][j] += av[i] * bv;
    }
  }
#pragma unroll
  for (int i = 0; i < RPT; ++i)
#pragma unroll
    for (int j = 0; j < CPT; ++j)
      V[(size_t)(d + N + r0 + i) * 256 + d + c0 + j] = -acc[i][j];
}

// ---------------- T = Ls * Vinv (tiled f32 GEMM); bacc -= T*muc partials -----
__global__ __launch_bounds__(256) void k_tgemm(const float* __restrict__ G,
                                               const float* __restrict__ Vinv,
                                               const float* __restrict__ means,
                                               const int* __restrict__ valid,
                                               unsigned short* __restrict__ Tb,
                                               float* __restrict__ bacc) {
  int l = blockIdx.y;
  int ti = blockIdx.x >> 2, tj = blockIdx.x & 3;
  unsigned short* Tbl = Tb + ((size_t)l << 16);
  int i0 = ti * 64, j0 = tj * 64;
  int t = threadIdx.x;
  if (!valid[l]) {
    if (tj == 0 && t < 64) bacc[l * 256 + i0 + t] = 0.0f;   // bvec = 0
    for (int idx = t; idx < 4096; idx += 256) {
      int i = idx >> 6, j = idx & 63;
      Tbl[(size_t)(i0 + i) * 256 + j0 + j] = f2bf((i0 + i) == (j0 + j) ? 1.0f : 0.0f);
    }
    return;
  }
  if (tj > ti) {
    for (int idx = t; idx < 4096; idx += 256) {
      int i = idx >> 6, j = idx & 63;
      Tbl[(size_t)(i0 + i) * 256 + j0 + j] = 0;
    }
    return;
  }
  const float* LTs = G + ((size_t)(8 + l) << 16);  // style L, col-major lower
  const float* V = Vinv + ((size_t)l << 16);

  __shared__ float As[64][260];
  __shared__ __align__(16) float Bs[256][68];

  for (int idx = t; idx < 64 * 256; idx += 256) {
    int k = idx >> 6, i = idx & 63;
    As[i][k] = (i0 + i >= k) ? LTs[(size_t)k * 256 + i0 + i] : 0.0f;
  }
  for (int idx = t; idx < 64 * 256; idx += 256) {
    int k = idx >> 6, j = idx & 63;
    Bs[k][j] = V[(size_t)k * 256 + j0 + j];
  }
  __syncthreads();

  int tx = t & 15, ty = t >> 4;
  float acc[4][4] = {};
  int klo = j0, khi = i0 + 64;
  for (int k = klo; k < khi; ++k) {
    float a0 = As[ty * 4 + 0][k], a1 = As[ty * 4 + 1][k];
    float a2 = As[ty * 4 + 2][k], a3 = As[ty * 4 + 3][k];
    float4 b = *(const float4*)&Bs[k][tx * 4];
    acc[0][0] += a0 * b.x; acc[0][1] += a0 * b.y; acc[0][2] += a0 * b.z; acc[0][3] += a0 * b.w;
    acc[1][0] += a1 * b.x; acc[1][1] += a1 * b.y; acc[1][2] += a1 * b.z; acc[1][3] += a1 * b.w;
    acc[2][0] += a2 * b.x; acc[2][1] += a2 * b.y; acc[2][2] += a2 * b.z; acc[2][3] += a2 * b.w;
    acc[3][0] += a3 * b.x; acc[3][1] += a3 * b.y; acc[3][2] += a3 * b.z; acc[3][3] += a3 * b.w;
  }
  float mc[4];
#pragma unroll
  for (int cc = 0; cc < 4; ++cc) mc[cc] = means[l * 256 + j0 + tx * 4 + cc];
#pragma unroll
  for (int rr = 0; rr < 4; ++rr) {
    int i = i0 + ty * 4 + rr;
    float partial = 0.0f;
#pragma unroll
    for (int cc = 0; cc < 4; ++cc) {
      Tbl[(size_t)i * 256 + j0 + tx * 4 + cc] = f2bf(acc[rr][cc]);
      partial += acc[rr][cc] * mc[cc];
    }
    atomicAdd(&bacc[l * 256 + i], -partial);
  }
}

// ---------------- out = T_l * x + b_l (128-px blocks, 8 waves, acc[4][4]) ----
__global__ __launch_bounds__(512) void k_outgemm(unsigned short* __restrict__ P,
                                                 const unsigned short* __restrict__ Tb,
                                                 const float* __restrict__ bvec,
                                                 const int* __restrict__ off) {
  long px0 = (long)blockIdx.x * 128;
  if (px0 >= off[8]) return;
  int l = 0;
  while (l < 7 && px0 >= off[l + 1]) ++l;
  const unsigned short* Tl = Tb + ((size_t)l << 16);

  __shared__ unsigned short As[256 * LDA];
  __shared__ unsigned short Bs[128 * LDA];
  __shared__ float bsh[256];

  int t = threadIdx.x, wave = t >> 6, lane = t & 63;
  int wrow = (wave & 3) * 64;
  int pq = (wave >> 2) * 64;                    // px half within 128
  if (t < 256) bsh[t] = bvec[l * 256 + t];

  f32x4 acc[4][4] = {};

  for (int kk = 0; kk < 256; kk += 32) {
#pragma unroll
    for (int it = 0; it < 2; ++it) {            // A: 256 rows x 32 k
      int slot = t + it * 512;
      int rr = slot >> 2, gg = slot & 3;
      *(uint4*)&As[rr * LDA + gg * 8] = *(const uint4*)&Tl[rr * 256 + kk + gg * 8];
    }
    {                                           // B: transpose-stage 32k x 128px
      int pg = t & 15, kr = t >> 4;
      uint4 v = *(const uint4*)&P[(size_t)(kk + kr) * MPAD + px0 + pg * 8];
      const unsigned short* vs = (const unsigned short*)&v;
      int krs = kr ^ ((pg & 3) << 3);           // k-block XOR swizzle (bank spread)
#pragma unroll
      for (int e = 0; e < 8; ++e) Bs[(pg * 8 + e) * LDA + krs] = vs[e];
    }
    __syncthreads();
    if (kk < wrow + 64) {                       // T is lower-triangular: skip dead k-tiles
      bf16x8 bfr[4];
#pragma unroll
      for (int fj = 0; fj < 4; ++fj) {
        int px = pq + fj * 16 + (lane & 15);
        int gs = (lane >> 4) ^ ((px >> 3) & 3);
        bfr[fj] = *(const bf16x8*)&Bs[px * LDA + gs * 8];
      }
#pragma unroll
      for (int fi = 0; fi < 4; ++fi) {
        if (wrow + fi * 16 + 15 >= kk) {
          bf16x8 afr = *(const bf16x8*)&As[(wrow + fi * 16 + (lane & 15)) * LDA + (lane >> 4) * 8];
#pragma unroll
          for (int fj = 0; fj < 4; ++fj)
            acc[fi][fj] = __builtin_amdgcn_mfma_f32_16x16x32_bf16(afr, bfr[fj], acc[fi][fj], 0, 0, 0);
        }
      }
    }
    __syncthreads();
  }
#pragma unroll
  for (int fi = 0; fi < 4; ++fi)
#pragma unroll
    for (int fj = 0; fj < 4; ++fj) {
      long p = px0 + pq + fj * 16 + (lane & 15);
#pragma unroll
      for (int rg = 0; rg < 4; ++rg) {
        int rr = wrow + fi * 16 + (lane >> 4) * 4 + rg;
        float v = acc[fi][fj][rg] + bsh[rr];
        P[(size_t)rr * MPAD + p] = f2bf(v);
      }
    }
}

// =============================================================================
extern "C" void kernel_launch(void* const* d_in, const int* in_sizes, int n_in,
                              void* d_out, int out_size, void* d_ws, size_t ws_size,
                              hipStream_t stream) {
  const float* cfeat = (const float*)d_in[0];
  const float* sfeat = (const float*)d_in[1];
  const int* seg_c   = (const int*)d_in[2];
  const int* seg_s   = (const int*)d_in[3];

  char* ws = (char*)d_ws;
  size_t o = 0;
  auto take = [&](size_t b) { size_t r = o; o += (b + 255) & ~(size_t)255; return r; };

  unsigned short* P  = (unsigned short*)(ws + take((size_t)NCH * MPAD * 2));
  size_t zero_b = o;
  float* G           = (float*)(ws + take((size_t)2 * 8 * 65536 * 4));
  float* Vinv        = (float*)(ws + take((size_t)8 * 65536 * 4));
  float* sum         = (float*)(ws + take((size_t)2 * 8 * 256 * 4));
  float* bacc        = (float*)(ws + take((size_t)8 * 256 * 4));
  int*   hist        = (int*)(ws + take((size_t)2 * 128 * 8 * 4));
  size_t zero_e = o;
  unsigned short* Tb = (unsigned short*)(ws + take((size_t)8 * 65536 * 2));
  float* Wg          = (float*)(ws + take((size_t)16 * 8 * 1024 * 4));
  int*   dst         = (int*)(ws + take((size_t)2 * M_PIX * 4));
  float* means       = (float*)(ws + take((size_t)2 * 8 * 256 * 4));
  int*   base        = (int*)(ws + take((size_t)2 * 128 * 8 * 4));
  int*   off         = (int*)(ws + take((size_t)2 * 9 * 4));
  int*   cnt         = (int*)(ws + take((size_t)2 * 8 * 4));
  int*   valid       = (int*)(ws + take((size_t)8 * 4));
  (void)ws_size; (void)n_in; (void)in_sizes; (void)out_size;

  hipMemsetAsync(ws + zero_b, 0, zero_e - zero_b, stream);

  k_hist<<<dim3(128), dim3(256), 0, stream>>>(seg_c, seg_s, hist);
  k_scan<<<dim3(1), dim3(256), 0, stream>>>(hist, base, off, cnt, valid);
  k_rank<<<dim3(128), dim3(256), 0, stream>>>(seg_c, seg_s, base, dst);

  // style (side 1) first, then content (side 0); P is reused, stream-serial.
  for (int s = 1; s >= 0; --s) {
    const float* feat = s ? sfeat : cfeat;
    const int* seg = s ? seg_s : seg_c;
    k_padzero<<<dim3(8, 16), dim3(256), 0, stream>>>(P, off + s * 9, cnt + s * 8);
    k_pack<<<dim3(128, 8), dim3(256), 0, stream>>>(feat, seg, dst + (size_t)s * M_PIX,
                                                   base + s * 1024, P);
    k_gram<<<dim3(260, 8, 3), dim3(256), 0, stream>>>(P, off + s * 9,
                                                      G + (size_t)s * 8 * 65536,
                                                      sum + (size_t)s * 8 * 256);
  }

  k_cov<<<dim3(16), dim3(256), 0, stream>>>(G, sum, cnt, means, bacc);
  for (int pb = 0; pb < 4; ++pb) {
    k_panel64<<<dim3(16), dim3(256), 0, stream>>>(G, Wg, pb);
    if (pb < 3) {
      int nts2 = (192 - 64 * pb) >> 6;
      k_trail64<<<dim3(16, (nts2 * (nts2 + 1)) >> 1), dim3(256), 0, stream>>>(G, pb);
    }
  }
  k_vlevel32w<<<dim3(32), dim3(256), 0, stream>>>(G, Wg, Vinv);
  k_vlevel<64><<<dim3(16), dim3(512), 0, stream>>>(G, Vinv);
  k_vlevel<128><<<dim3(8), dim3(512), 0, stream>>>(G, Vinv);
  k_tgemm<<<dim3(16, 8), dim3(256), 0, stream>>>(G, Vinv, means, valid, Tb, bacc);
  k_outgemm<<<dim3(2080), dim3(512), 0, stream>>>(P, Tb, bacc, off);
  k_unpack<<<dim3(128, 8), dim3(256), 0, stream>>>(P, seg_c, dst, base, (float*)d_out);
}